// Round 2
// baseline (1733.734 us; speedup 1.0000x reference)
//
#include <hip/hip_runtime.h>

typedef unsigned short u16;
typedef short s16x8 __attribute__((ext_vector_type(8)));
typedef float f32x4 __attribute__((ext_vector_type(4)));

#define LAYERS   64
#define M_NODES  2048
#define DIM      128
#define FD       512
#define CHUNK    16
#define NBLK     128     // M_NODES / CHUNK
#define TPB      512     // 8 waves
#define XPAD     136     // 128 + 8 pad u16 (16B-aligned rows, breaks bank aliasing)
#define ZPAD     516     // 512 + 4 pad fp32 words

__device__ __forceinline__ u16 f2bf(float f) {
    union { float f; unsigned int i; } v; v.f = f;
    unsigned int r = (v.i + 0x7FFFu + ((v.i >> 16) & 1u)) >> 16;
    return (u16)r;
}
__device__ __forceinline__ float sigm(float x) {
    return 1.0f / (1.0f + __builtin_exp2f(-1.44269504f * x));
}
__device__ __forceinline__ float tanh_f(float x) {
    float ax = __builtin_fabsf(x);
    float t  = __builtin_exp2f(-2.88539008f * ax);   // exp(-2|x|)
    float r  = (1.0f - t) / (1.0f + t);
    return __builtin_copysignf(r, x);
}

// ---------------- layer 0: emb[m] = basic_table[basic_names[m]]  (fp32 copy) ----------------
__global__ void l0_kernel(const int* __restrict__ names, const float* __restrict__ table,
                          float* __restrict__ emb) {
    int v = blockIdx.x * blockDim.x + threadIdx.x;      // 2048 rows * 32 float4
    if (v >= M_NODES * (DIM / 4)) return;
    int row = v >> 5, c = v & 31;
    const float4* src = (const float4*)(table + (size_t)names[row] * DIM);
    ((float4*)(emb + (size_t)row * DIM))[c] = src[c];
}

// ------------- repack W_m,U_m,W_s,U_s (fp32) into bf16 MFMA B-fragments in d_ws -------------
// packed[(((mat*4 + kc)*32 + ntile)*64 + lane)*8 + j] = bf16(B[kc*32 + (lane>>4)*8 + j][ntile*16 + (lane&15)])
__global__ void repack_kernel(const float* __restrict__ Wm, const float* __restrict__ Um,
                              const float* __restrict__ Ws, const float* __restrict__ Us,
                              u16* __restrict__ packed) {
    int t = blockIdx.x * blockDim.x + threadIdx.x;      // 4*4*32*64 = 32768 threads
    if (t >= 4 * 4 * 32 * 64) return;
    int lane = t & 63, ntg = (t >> 6) & 31, kc = (t >> 11) & 3, mat = t >> 13;
    const float* B = (mat == 0) ? Wm : (mat == 1) ? Um : (mat == 2) ? Ws : Us;
    int q = lane >> 4, nl = lane & 15;
    int kb = kc * 32 + q * 8;
    int n  = ntg * 16 + nl;
    u16* dst = packed + ((((size_t)mat * 4 + kc) * 32 + ntg) * 64 + lane) * 8;
    #pragma unroll
    for (int j = 0; j < 8; j++) dst[j] = f2bf(B[(size_t)(kb + j) * FD + n]);
}

// ----------------------------- per-layer kernel -----------------------------
template <bool PACKED>
__global__ __launch_bounds__(TPB, 2) void layer_kernel(
    float* __restrict__ emb, const int* __restrict__ prop_ids, const int* __restrict__ super_ids,
    const float* __restrict__ Wm, const float* __restrict__ Um, const float* __restrict__ bm,
    const float* __restrict__ Ws, const float* __restrict__ Us, const float* __restrict__ bs,
    const float* __restrict__ empty, const u16* __restrict__ packed, int l) {

    // slots 0..3: prop embeddings p=0..3 (slot 0 reused for h_m after LSTM_m)
    // slots 4..5: super embeddings s=0..1
    __shared__ __align__(16) u16  xs[6][CHUNK][XPAD];   // bf16 A-operand tiles
    __shared__ __align__(16) u16  hbuf[CHUNK][XPAD];    // bf16 h state
    __shared__ __align__(16) u16  empty_s[XPAD];
    __shared__ float              zbuf[CHUNK][ZPAD];    // fp32 gate pre-activations

    const int tid  = threadIdx.x;
    const int b    = blockIdx.x;
    const int g0   = b * CHUNK;
    const size_t row0 = (size_t)l * M_NODES + g0;

    const int wv   = tid >> 6;          // wave 0..7 -> z columns [wv*64, wv*64+64)
    const int lane = tid & 63;
    const int q    = lane >> 4, nl = lane & 15;
    const int d_nl = tid & 127;         // nonlinearity: this thread's d
    const int mb   = tid >> 7;          // nonlinearity: m = 4*r2 + mb

    // ---- gather phase: fp32 global rows -> bf16 LDS tiles ----
    if (tid < 384) {
        int quarter = tid & 3;          // 32 elements each
        int r    = tid >> 2;            // 0..95
        int slot = r >> 4;              // 0..5
        int node = r & 15;
        size_t idx;
        if (slot < 4) idx = (size_t)prop_ids [((size_t)l * M_NODES + g0 + node) * 4 + slot];
        else          idx = (size_t)super_ids[((size_t)l * M_NODES + g0 + node) * 2 + (slot - 4)];
        const float4* src = (const float4*)(emb + idx * DIM);
        u16* dst = &xs[slot][node][0];
        int e0 = quarter * 32;
        #pragma unroll
        for (int j = 0; j < 8; j++) {
            float4 v = src[(e0 >> 2) + j];
            int o = e0 + j * 4;
            dst[o] = f2bf(v.x); dst[o + 1] = f2bf(v.y);
            dst[o + 2] = f2bf(v.z); dst[o + 3] = f2bf(v.w);
        }
    } else {
        int d = tid - 384;              // 0..127
        empty_s[d] = f2bf(empty[d]);
    }
    for (int j = tid; j < CHUNK * XPAD; j += TPB) ((u16*)hbuf)[j] = 0;
    __syncthreads();

    auto load_bfrag_packed = [&](int mat, int kc, int nt) -> s16x8 {
        return *(const s16x8*)(packed + ((((size_t)mat * 4 + kc) * 32 + (wv * 4 + nt)) * 64 + lane) * 8);
    };
    auto load_bfrag_direct = [&](const float* B, int kc, int nt) -> s16x8 {
        int kb = kc * 32 + q * 8;
        int n  = wv * 64 + nt * 16 + nl;
        s16x8 f;
        #pragma unroll
        for (int j = 0; j < 8; j++) f[j] = (short)f2bf(B[(size_t)(kb + j) * FD + n]);
        return f;
    };
    auto load_afrag = [&](const u16* X /* [CHUNK][XPAD] base */, int kc) -> s16x8 {
        return *(const s16x8*)(X + (size_t)nl * XPAD + kc * 32 + q * 8);
    };

    auto run_phase = [&](const float* Wg, const float* Ug, const float* bias,
                         int matW, int matU, int nsteps, const int* slots,
                         bool write_hm, bool write_out) {
        // weight-stationary B-fragments for the whole phase (128 VGPRs)
        s16x8 wf[4][4], uf[4][4];
        #pragma unroll
        for (int kc = 0; kc < 4; kc++) {
            #pragma unroll
            for (int nt = 0; nt < 4; nt++) {
                if (PACKED) { wf[kc][nt] = load_bfrag_packed(matW, kc, nt);
                              uf[kc][nt] = load_bfrag_packed(matU, kc, nt); }
                else        { wf[kc][nt] = load_bfrag_direct(Wg, kc, nt);
                              uf[kc][nt] = load_bfrag_direct(Ug, kc, nt); }
            }
        }
        float bi = bias[d_nl],       bf_ = bias[128 + d_nl];
        float bg = bias[256 + d_nl], bo  = bias[384 + d_nl];
        float cc[4] = {0.f, 0.f, 0.f, 0.f};

        for (int t = 0; t < nsteps; t++) {
            // ---- z = x_t @ W + h @ U (fp32 acc via bf16 MFMA) ----
            f32x4 acc[4];
            #pragma unroll
            for (int nt = 0; nt < 4; nt++) acc[nt] = (f32x4){0.f, 0.f, 0.f, 0.f};
            int s = slots[t];
            #pragma unroll
            for (int kc = 0; kc < 4; kc++) {
                s16x8 a = (s < 0) ? *(const s16x8*)(&empty_s[kc * 32 + q * 8])
                                  : load_afrag(&xs[s][0][0], kc);
                #pragma unroll
                for (int nt = 0; nt < 4; nt++)
                    acc[nt] = __builtin_amdgcn_mfma_f32_16x16x32_bf16(a, wf[kc][nt], acc[nt], 0, 0, 0);
            }
            #pragma unroll
            for (int kc = 0; kc < 4; kc++) {
                s16x8 a = load_afrag(&hbuf[0][0], kc);
                #pragma unroll
                for (int nt = 0; nt < 4; nt++)
                    acc[nt] = __builtin_amdgcn_mfma_f32_16x16x32_bf16(a, uf[kc][nt], acc[nt], 0, 0, 0);
            }
            // D layout: col = lane&15, row = (lane>>4)*4 + reg
            #pragma unroll
            for (int nt = 0; nt < 4; nt++) {
                int col = wv * 64 + nt * 16 + nl;
                #pragma unroll
                for (int r2 = 0; r2 < 4; r2++) zbuf[q * 4 + r2][col] = acc[nt][r2];
            }
            __syncthreads();

            // ---- gates + state update; thread owns (m = 4*r2 + mb, d = d_nl) ----
            bool last = (t == nsteps - 1);
            #pragma unroll
            for (int r2 = 0; r2 < 4; r2++) {
                int m = (r2 << 2) + mb;
                float zi = zbuf[m][d_nl]        + bi;
                float zf = zbuf[m][128 + d_nl]  + bf_;
                float zg = zbuf[m][256 + d_nl]  + bg;
                float zo = zbuf[m][384 + d_nl]  + bo;
                float c  = sigm(zf) * cc[r2] + sigm(zi) * tanh_f(zg);
                cc[r2] = c;
                float h  = sigm(zo) * tanh_f(c);
                hbuf[m][d_nl] = f2bf(h);
                if (last && write_hm)  xs[0][m][d_nl] = f2bf(h);            // h_m for seq_s[2]
                if (last && write_out) emb[(row0 + m) * DIM + d_nl] = h;    // fp32 layer output
            }
            __syncthreads();
        }
    };

    {   // LSTM_m: seq = [empty, prop0..3]
        const int slots_m[5] = {-1, 0, 1, 2, 3};
        run_phase(Wm, Um, bm, 0, 1, 5, slots_m, true, false);
    }
    // reset h for second LSTM
    for (int j = tid; j < CHUNK * XPAD; j += TPB) ((u16*)hbuf)[j] = 0;
    __syncthreads();
    {   // LSTM_s: seq = [sup0, sup1, h_m]
        const int slots_s[3] = {4, 5, 0};
        run_phase(Ws, Us, bs, 2, 3, 3, slots_s, false, true);
    }
}

extern "C" void kernel_launch(void* const* d_in, const int* in_sizes, int n_in,
                              void* d_out, int out_size, void* d_ws, size_t ws_size,
                              hipStream_t stream) {
    const int*   names = (const int*)d_in[0];
    const int*   pids  = (const int*)d_in[1];
    const int*   sids  = (const int*)d_in[2];
    const float* table = (const float*)d_in[3];
    const float* Wm    = (const float*)d_in[4];
    const float* Um    = (const float*)d_in[5];
    const float* bm    = (const float*)d_in[6];
    const float* Ws    = (const float*)d_in[7];
    const float* Us    = (const float*)d_in[8];
    const float* bs    = (const float*)d_in[9];
    const float* empt  = (const float*)d_in[10];
    float* emb  = (float*)d_out;
    u16* packed = (u16*)d_ws;

    l0_kernel<<<256, 256, 0, stream>>>(names, table, emb);

    const size_t packed_bytes = (size_t)4 * 4 * 32 * 64 * 8 * sizeof(u16);  // 512 KB
    if (ws_size >= packed_bytes) {
        repack_kernel<<<128, 256, 0, stream>>>(Wm, Um, Ws, Us, packed);
        for (int l = 1; l < LAYERS; l++)
            layer_kernel<true><<<NBLK, TPB, 0, stream>>>(emb, pids, sids, Wm, Um, bm,
                                                         Ws, Us, bs, empt, packed, l);
    } else {
        for (int l = 1; l < LAYERS; l++)
            layer_kernel<false><<<NBLK, TPB, 0, stream>>>(emb, pids, sids, Wm, Um, bm,
                                                          Ws, Us, bs, empt, packed, l);
    }
}

// Round 3
// 1269.385 us; speedup vs baseline: 1.3658x; 1.3658x over previous
//
#include <hip/hip_runtime.h>

typedef unsigned short u16;
typedef short s16x8 __attribute__((ext_vector_type(8)));
typedef float f32x4 __attribute__((ext_vector_type(4)));

#define LAYERS   64
#define M_NODES  2048
#define DIM      128
#define FD       512
#define CHUNK    16
#define NBLK     128     // M_NODES / CHUNK
#define TPB      512     // 8 waves; wave wv owns hidden dims [wv*16, wv*16+16)
#define XPAD     136     // 128 + 8 pad u16 (16B-aligned rows)

__device__ __forceinline__ u16 f2bf(float f) {
    union { float f; unsigned int i; } v; v.f = f;
    unsigned int r = (v.i + 0x7FFFu + ((v.i >> 16) & 1u)) >> 16;
    return (u16)r;
}
__device__ __forceinline__ float sigm(float x) {
    // 1/(1+exp(-x)) with v_rcp_f32 (≈1e-6 rel err, fine vs bf16 noise)
    return __builtin_amdgcn_rcpf(1.0f + __builtin_exp2f(-1.44269504f * x));
}
__device__ __forceinline__ float tanh_f(float x) {
    float ax = __builtin_fabsf(x);
    float t  = __builtin_exp2f(-2.88539008f * ax);   // exp(-2|x|)
    float r  = (1.0f - t) * __builtin_amdgcn_rcpf(1.0f + t);
    return __builtin_copysignf(r, x);
}

// ---------------- layer 0: emb[m] = basic_table[basic_names[m]]  (fp32 copy) ----------------
__global__ void l0_kernel(const int* __restrict__ names, const float* __restrict__ table,
                          float* __restrict__ emb) {
    int v = blockIdx.x * blockDim.x + threadIdx.x;      // 2048 rows * 32 float4
    if (v >= M_NODES * (DIM / 4)) return;
    int row = v >> 5, c = v & 31;
    const float4* src = (const float4*)(table + (size_t)names[row] * DIM);
    ((float4*)(emb + (size_t)row * DIM))[c] = src[c];
}

// ------------- repack W_m,U_m,W_s,U_s (fp32) into bf16 MFMA B-fragments in d_ws -------------
// packed[(((mat*4 + kc)*32 + ntile)*64 + lane)*8 + j] = bf16(B[kc*32 + (lane>>4)*8 + j][ntile*16 + (lane&15)])
__global__ void repack_kernel(const float* __restrict__ Wm, const float* __restrict__ Um,
                              const float* __restrict__ Ws, const float* __restrict__ Us,
                              u16* __restrict__ packed) {
    int t = blockIdx.x * blockDim.x + threadIdx.x;      // 4*4*32*64 = 32768 threads
    if (t >= 4 * 4 * 32 * 64) return;
    int lane = t & 63, ntg = (t >> 6) & 31, kc = (t >> 11) & 3, mat = t >> 13;
    const float* B = (mat == 0) ? Wm : (mat == 1) ? Um : (mat == 2) ? Ws : Us;
    int q = lane >> 4, nl = lane & 15;
    int kb = kc * 32 + q * 8;
    int n  = ntg * 16 + nl;
    u16* dst = packed + ((((size_t)mat * 4 + kc) * 32 + ntg) * 64 + lane) * 8;
    #pragma unroll
    for (int j = 0; j < 8; j++) dst[j] = f2bf(B[(size_t)(kb + j) * FD + n]);
}

// ----------------------------- per-layer kernel -----------------------------
// Gate-local N split: wave wv computes z columns {g*128 + wv*16 + nl} for g=0..3,
// so each lane ends the MFMA holding all 4 gate pre-activations for
// (m = quad*4 + r2, d = wv*16 + nl) -> gates are register-only, no z LDS round-trip.
// Only h crosses waves: bf16 double-buffered hbuf, ONE barrier per timestep.
template <bool PACKED>
__global__ __launch_bounds__(TPB, 2) void layer_kernel(
    float* __restrict__ emb, const int* __restrict__ prop_ids, const int* __restrict__ super_ids,
    const float* __restrict__ Wm, const float* __restrict__ Um, const float* __restrict__ bm,
    const float* __restrict__ Ws, const float* __restrict__ Us, const float* __restrict__ bs,
    const float* __restrict__ empty, const u16* __restrict__ packed, int l) {

    // slots 0..3: prop embeddings (slot 0 reused for h_m); slots 4..5: super embeddings
    __shared__ __align__(16) u16  xs[6][CHUNK][XPAD];   // bf16 A-operand tiles
    __shared__ __align__(16) u16  hbuf[2][CHUNK][XPAD]; // bf16 h state, double-buffered
    __shared__ __align__(16) u16  empty_s[XPAD];

    const int tid  = threadIdx.x;
    const int b    = blockIdx.x;
    const int g0   = b * CHUNK;
    const size_t row0 = (size_t)l * M_NODES + g0;

    const int wv   = tid >> 6;          // 0..7
    const int lane = tid & 63;
    const int q    = lane >> 4, nl = lane & 15;
    const int d    = wv * 16 + nl;      // this lane's hidden dim

    // ---- gather phase: fp32 global rows -> bf16 LDS tiles ----
    if (tid < 384) {
        int quarter = tid & 3;          // 32 elements each
        int r    = tid >> 2;            // 0..95
        int slot = r >> 4;              // 0..5
        int node = r & 15;
        size_t idx;
        if (slot < 4) idx = (size_t)prop_ids [((size_t)l * M_NODES + g0 + node) * 4 + slot];
        else          idx = (size_t)super_ids[((size_t)l * M_NODES + g0 + node) * 2 + (slot - 4)];
        const float4* src = (const float4*)(emb + idx * DIM);
        u16* dst = &xs[slot][node][0];
        int e0 = quarter * 32;
        #pragma unroll
        for (int j = 0; j < 8; j++) {
            float4 v = src[(e0 >> 2) + j];
            int o = e0 + j * 4;
            dst[o] = f2bf(v.x); dst[o + 1] = f2bf(v.y);
            dst[o + 2] = f2bf(v.z); dst[o + 3] = f2bf(v.w);
        }
    } else if (tid < 384 + 128) {
        int dd = tid - 384;             // 0..127
        empty_s[dd] = f2bf(empty[dd]);
    }
    __syncthreads();

    auto load_bfrag_packed = [&](int mat, int kc, int g) -> s16x8 {
        return *(const s16x8*)(packed + ((((size_t)mat * 4 + kc) * 32 + (g * 8 + wv)) * 64 + lane) * 8);
    };
    auto load_bfrag_direct = [&](const float* B, int kc, int g) -> s16x8 {
        int kb = kc * 32 + q * 8;
        int n  = g * 128 + d;
        s16x8 f;
        #pragma unroll
        for (int j = 0; j < 8; j++) f[j] = (short)f2bf(B[(size_t)(kb + j) * FD + n]);
        return f;
    };
    auto load_afrag = [&](const u16* X /* [CHUNK][XPAD] base */, int kc) -> s16x8 {
        return *(const s16x8*)(X + (size_t)nl * XPAD + kc * 32 + q * 8);
    };

    auto run_phase = [&](const float* Wg, const float* Ug, const float* bias,
                         int matW, int matU, int nsteps, const int* slots,
                         bool write_hm, bool write_out) {
        // weight-stationary B-fragments for the whole phase: [kc][gate], 128 VGPRs
        s16x8 wf[4][4], uf[4][4];
        #pragma unroll
        for (int kc = 0; kc < 4; kc++) {
            #pragma unroll
            for (int g = 0; g < 4; g++) {
                if (PACKED) { wf[kc][g] = load_bfrag_packed(matW, kc, g);
                              uf[kc][g] = load_bfrag_packed(matU, kc, g); }
                else        { wf[kc][g] = load_bfrag_direct(Wg, kc, g);
                              uf[kc][g] = load_bfrag_direct(Ug, kc, g); }
            }
        }
        float bz[4];
        #pragma unroll
        for (int g = 0; g < 4; g++) bz[g] = bias[g * 128 + d];
        float cc[4] = {0.f, 0.f, 0.f, 0.f};

        #pragma unroll 1
        for (int t = 0; t < nsteps; t++) {
            int s = slots[t];
            f32x4 acc[4];
            #pragma unroll
            for (int g = 0; g < 4; g++) acc[g] = (f32x4){0.f, 0.f, 0.f, 0.f};
            // x_t @ W (xs static after gather; no sync needed)
            #pragma unroll
            for (int kc = 0; kc < 4; kc++) {
                s16x8 a = (s < 0) ? *(const s16x8*)(&empty_s[kc * 32 + q * 8])
                                  : load_afrag(&xs[s][0][0], kc);
                #pragma unroll
                for (int g = 0; g < 4; g++)
                    acc[g] = __builtin_amdgcn_mfma_f32_16x16x32_bf16(a, wf[kc][g], acc[g], 0, 0, 0);
            }
            // h_{t-1} @ U  (t=0: h=0, skip — also makes hbuf init unnecessary)
            if (t > 0) {
                __syncthreads();   // h_{t-1} writes visible
                const u16* hb = &hbuf[(t - 1) & 1][0][0];
                #pragma unroll
                for (int kc = 0; kc < 4; kc++) {
                    s16x8 a = load_afrag(hb, kc);
                    #pragma unroll
                    for (int g = 0; g < 4; g++)
                        acc[g] = __builtin_amdgcn_mfma_f32_16x16x32_bf16(a, uf[kc][g], acc[g], 0, 0, 0);
                }
            }
            // gates, fully in-register: lane owns (m = q*4 + r2, d), all 4 gates
            bool last = (t == nsteps - 1);
            #pragma unroll
            for (int r2 = 0; r2 < 4; r2++) {
                int m = q * 4 + r2;
                float zi = acc[0][r2] + bz[0];
                float zf = acc[1][r2] + bz[1];
                float zg = acc[2][r2] + bz[2];
                float zo = acc[3][r2] + bz[3];
                float c  = sigm(zf) * cc[r2] + sigm(zi) * tanh_f(zg);
                cc[r2] = c;
                float h  = sigm(zo) * tanh_f(c);
                if (!last)          hbuf[t & 1][m][d] = f2bf(h);
                else if (write_hm)  xs[0][m][d] = f2bf(h);             // h_m -> seq_s[2]
                else if (write_out) emb[(row0 + m) * DIM + d] = h;     // fp32 layer output
            }
        }
    };

    {   // LSTM_m: seq = [empty, prop0..3]
        const int slots_m[5] = {-1, 0, 1, 2, 3};
        run_phase(Wm, Um, bm, 0, 1, 5, slots_m, true, false);
    }
    // no hbuf reset needed: phase-2 t=0 skips h@U and overwrites hbuf[0]
    {   // LSTM_s: seq = [sup0, sup1, h_m]  (h_m write is covered by phase-2 t=1 barrier)
        const int slots_s[3] = {4, 5, 0};
        run_phase(Ws, Us, bs, 2, 3, 3, slots_s, false, true);
    }
}

extern "C" void kernel_launch(void* const* d_in, const int* in_sizes, int n_in,
                              void* d_out, int out_size, void* d_ws, size_t ws_size,
                              hipStream_t stream) {
    const int*   names = (const int*)d_in[0];
    const int*   pids  = (const int*)d_in[1];
    const int*   sids  = (const int*)d_in[2];
    const float* table = (const float*)d_in[3];
    const float* Wm    = (const float*)d_in[4];
    const float* Um    = (const float*)d_in[5];
    const float* bm    = (const float*)d_in[6];
    const float* Ws    = (const float*)d_in[7];
    const float* Us    = (const float*)d_in[8];
    const float* bs    = (const float*)d_in[9];
    const float* empt  = (const float*)d_in[10];
    float* emb  = (float*)d_out;
    u16* packed = (u16*)d_ws;

    l0_kernel<<<256, 256, 0, stream>>>(names, table, emb);

    const size_t packed_bytes = (size_t)4 * 4 * 32 * 64 * 8 * sizeof(u16);  // 512 KB
    if (ws_size >= packed_bytes) {
        repack_kernel<<<128, 256, 0, stream>>>(Wm, Um, Ws, Us, packed);
        for (int l = 1; l < LAYERS; l++)
            layer_kernel<true><<<NBLK, TPB, 0, stream>>>(emb, pids, sids, Wm, Um, bm,
                                                         Ws, Us, bs, empt, packed, l);
    } else {
        for (int l = 1; l < LAYERS; l++)
            layer_kernel<false><<<NBLK, TPB, 0, stream>>>(emb, pids, sids, Wm, Um, bm,
                                                          Ws, Us, bs, empt, packed, l);
    }
}